// Round 1
// baseline (4249.958 us; speedup 1.0000x reference)
//
#include <hip/hip_runtime.h>

#define N_NODESC 50000
#define N_EDGESC 1600000
#define FEAT 128
#define NREL 8
#define NSEG (N_NODESC * NREL)
#define NGRAPH 64
#define TM 64

static inline size_t align256(size_t x) { return (x + 255) & ~(size_t)255; }

// ---------------- utility: zero ints ----------------
__global__ void k_zero(int* __restrict__ p, int n) {
  int i = blockIdx.x * blockDim.x + threadIdx.x;
  int stride = gridDim.x * blockDim.x;
  for (; i < n; i += stride) p[i] = 0;
}

// ---------------- edge type + segment + histogram ----------------
__global__ void k_edge_hist(const int* __restrict__ ei, const float* __restrict__ eattr,
                            int* __restrict__ seg, int* __restrict__ cnt) {
  int e = blockIdx.x * blockDim.x + threadIdx.x;
  if (e >= N_EDGESC) return;
  int dst = ei[N_EDGESC + e];  // row 1
  const float4* ap = (const float4*)(eattr + (size_t)e * 8);
  float4 a0 = ap[0], a1 = ap[1];
  int ty = 0;
  if (a0.y > 0.5f) ty = 1;
  if (a0.z > 0.5f) ty = 2;
  if (a0.w > 0.5f) ty = 3;
  if (a1.x > 0.5f) ty = 4;
  if (a1.y > 0.5f) ty = 5;
  if (a1.z > 0.5f) ty = 6;
  if (a1.w > 0.5f) ty = 7;
  int s = dst * NREL + ty;
  seg[e] = s;
  atomicAdd(&cnt[s], 1);
}

// ---------------- 3-kernel exclusive scan over NSEG counts ----------------
// scan1: per-block (4096 elems) inclusive scan -> outIncl, block totals -> bsums
__global__ void k_scan1(const int* __restrict__ cnt, int* __restrict__ outIncl,
                        int* __restrict__ bsums, int n) {
  __shared__ int sd[256];
  int t = threadIdx.x;
  int base = blockIdx.x * 4096 + t * 16;
  int v[16];
  int s = 0;
#pragma unroll
  for (int j = 0; j < 16; ++j) {
    int idx = base + j;
    int x = (idx < n) ? cnt[idx] : 0;
    s += x;
    v[j] = s;
  }
  sd[t] = s;
  __syncthreads();
  for (int off = 1; off < 256; off <<= 1) {
    int add = (t >= off) ? sd[t - off] : 0;
    __syncthreads();
    sd[t] += add;
    __syncthreads();
  }
  int prev = (t > 0) ? sd[t - 1] : 0;
#pragma unroll
  for (int j = 0; j < 16; ++j) {
    int idx = base + j;
    if (idx < n) outIncl[idx] = prev + v[j];
  }
  if (t == 255) bsums[blockIdx.x] = sd[255];
}

__global__ void k_scan2(int* __restrict__ bsums, int nb) {
  if (blockIdx.x == 0 && threadIdx.x == 0) {
    int acc = 0;
    for (int i = 0; i < nb; ++i) {
      int x = bsums[i];
      bsums[i] = acc;
      acc += x;
    }
  }
}

__global__ void k_scan3(int* __restrict__ offsets, const int* __restrict__ bsums, int n) {
  int i = blockIdx.x * blockDim.x + threadIdx.x;
  if (i == 0) offsets[0] = 0;
  if (i < n) offsets[i + 1] += bsums[i >> 12];  // 4096 per chunk
}

// ---------------- stable-enough scatter into CSR ----------------
__global__ void k_scatter(const int* __restrict__ ei, const int* __restrict__ seg,
                          const int* __restrict__ offsets, int* __restrict__ cursor,
                          int* __restrict__ ssrc) {
  int e = blockIdx.x * blockDim.x + threadIdx.x;
  if (e >= N_EDGESC) return;
  int s = seg[e];
  int p = offsets[s] + atomicAdd(&cursor[s], 1);
  ssrc[p] = ei[e];  // src = row 0
}

// ---------------- fused RGCN layer: aggregate (LDS) + GEMM + root + bias + relu ----------------
// block = 256 threads, tile = 64 nodes. K loop over 9 "relations" (8 rels + root).
__global__ __launch_bounds__(256, 3) void k_layer(
    const float* __restrict__ in, const float* __restrict__ W,
    const float* __restrict__ root, const float* __restrict__ bias,
    const int* __restrict__ offsets, const int* __restrict__ ssrc,
    float* __restrict__ out) {
  __shared__ float aT[FEAT * 68];    // transposed agg tile [k=128][m=64 pad 68]
  __shared__ float wlds[32 * FEAT];  // W chunk [32 rows][128 cols]

  const int t = threadIdx.x;
  const int tx = t & 15;    // output col group: cols tx*8 .. tx*8+7
  const int tyq = t >> 4;   // output row group: rows tyq*4 .. tyq*4+3
  const int i = t & 127;    // feature lane for aggregation
  const int g = t >> 7;     // node-interleave group (0/1)
  const int n0 = blockIdx.x * TM;

  float acc[4][8];
#pragma unroll
  for (int a = 0; a < 4; ++a)
#pragma unroll
    for (int b = 0; b < 8; ++b) acc[a][b] = 0.f;

  for (int r = 0; r < 9; ++r) {
    // ---- aggregation phase ----
    if (r < NREL) {
      for (int mm = g; mm < TM; mm += 2) {
        int n = n0 + mm;
        float s = 0.f;
        if (n < N_NODESC) {
          int sidx = n * NREL + r;
          int beg = offsets[sidx], end = offsets[sidx + 1];
          for (int e = beg; e < end; ++e) {
            s += in[(size_t)ssrc[e] * FEAT + i];
          }
          int c = end - beg;
          if (c > 0) s /= (float)c;  // mean; c==0 -> 0 matches max(cnt,1)
        }
        aT[i * 68 + mm] = s;
      }
    } else {
      for (int mm = g; mm < TM; mm += 2) {
        int n = n0 + mm;
        aT[i * 68 + mm] = (n < N_NODESC) ? in[(size_t)n * FEAT + i] : 0.f;
      }
    }
    __syncthreads();

    const float* Wr = (r < NREL) ? (W + (size_t)r * FEAT * FEAT) : root;
    // ---- GEMM phase: 4 chunks of 32 k-rows ----
    for (int kc = 0; kc < 4; ++kc) {
      const float* wsrc = Wr + kc * 32 * FEAT + t * 16;
      float4* wd = (float4*)&wlds[t * 16];
#pragma unroll
      for (int j = 0; j < 4; ++j) wd[j] = ((const float4*)wsrc)[j];
      __syncthreads();
#pragma unroll
      for (int kk = 0; kk < 32; ++kk) {
        float a4[4], w8[8];
        *(float4*)a4 = *(const float4*)&aT[(kc * 32 + kk) * 68 + tyq * 4];
        *(float4*)w8 = *(const float4*)&wlds[kk * FEAT + tx * 8];
        *(float4*)(w8 + 4) = *(const float4*)&wlds[kk * FEAT + tx * 8 + 4];
#pragma unroll
        for (int a = 0; a < 4; ++a)
#pragma unroll
          for (int b = 0; b < 8; ++b)
            acc[a][b] = fmaf(a4[a], w8[b], acc[a][b]);
      }
      __syncthreads();  // also protects aT before next relation's aggregation
    }
  }

  // ---- epilogue: bias + relu + store ----
  float bia[8];
  *(float4*)bia = *(const float4*)&bias[tx * 8];
  *(float4*)(bia + 4) = *(const float4*)&bias[tx * 8 + 4];
#pragma unroll
  for (int a = 0; a < 4; ++a) {
    int n = n0 + tyq * 4 + a;
    if (n < N_NODESC) {
      float o[8];
#pragma unroll
      for (int b = 0; b < 8; ++b) {
        float v = acc[a][b] + bia[b];
        o[b] = v > 0.f ? v : 0.f;
      }
      *(float4*)&out[(size_t)n * FEAT + tx * 8] = *(float4*)o;
      *(float4*)&out[(size_t)n * FEAT + tx * 8 + 4] = *(float4*)(o + 4);
    }
  }
}

// ---------------- global mean pool (batch sorted) + final linear ----------------
__global__ void k_pool(const float* __restrict__ h, const int* __restrict__ batch,
                       const float* __restrict__ lw, const float* __restrict__ lb,
                       float* __restrict__ out) {
  __shared__ float prow[FEAT];
  int gidx = blockIdx.x, t = threadIdx.x;
  // lower_bound(batch, gidx) and lower_bound(batch, gidx+1)
  int lo = 0, hi = N_NODESC;
  while (lo < hi) {
    int mid = (lo + hi) >> 1;
    if (batch[mid] < gidx) lo = mid + 1; else hi = mid;
  }
  int start = lo;
  hi = N_NODESC;
  while (lo < hi) {
    int mid = (lo + hi) >> 1;
    if (batch[mid] < gidx + 1) lo = mid + 1; else hi = mid;
  }
  int end = lo;
  float s = 0.f;
  for (int n = start; n < end; ++n) s += h[(size_t)n * FEAT + t];
  int c = end - start;
  prow[t] = (c > 0) ? s / (float)c : 0.f;
  __syncthreads();
  float acc = lb[t];
  for (int k = 0; k < FEAT; ++k) acc = fmaf(prow[k], lw[k * FEAT + t], acc);
  out[gidx * FEAT + t] = acc;
}

extern "C" void kernel_launch(void* const* d_in, const int* in_sizes, int n_in,
                              void* d_out, int out_size, void* d_ws, size_t ws_size,
                              hipStream_t stream) {
  const float* x = (const float*)d_in[0];
  const int* ei = (const int*)d_in[1];
  const float* eattr = (const float*)d_in[2];
  const int* batch = (const int*)d_in[3];
  const float* W1 = (const float*)d_in[4];
  const float* r1 = (const float*)d_in[5];
  const float* b1 = (const float*)d_in[6];
  const float* W2 = (const float*)d_in[7];
  const float* r2 = (const float*)d_in[8];
  const float* b2 = (const float*)d_in[9];
  const float* W3 = (const float*)d_in[10];
  const float* r3 = (const float*)d_in[11];
  const float* b3 = (const float*)d_in[12];
  const float* lw = (const float*)d_in[13];
  const float* lb = (const float*)d_in[14];
  float* out = (float*)d_out;

  // workspace carve (~69 MB)
  char* p = (char*)d_ws;
  auto alloc = [&](size_t bytes) { char* q = p; p += align256(bytes); return q; };
  int* seg = (int*)alloc(sizeof(int) * (size_t)N_EDGESC);
  int* cntcur = (int*)alloc(sizeof(int) * (size_t)2 * NSEG);
  int* cnt = cntcur;
  int* cursor = cntcur + NSEG;
  int* offsets = (int*)alloc(sizeof(int) * (size_t)(NSEG + 1));
  int* bsums = (int*)alloc(sizeof(int) * 1024);
  int* ssrc = (int*)alloc(sizeof(int) * (size_t)N_EDGESC);
  float* h1 = (float*)alloc(sizeof(float) * (size_t)N_NODESC * FEAT);
  float* h2 = (float*)alloc(sizeof(float) * (size_t)N_NODESC * FEAT);
  (void)ws_size; (void)n_in; (void)in_sizes; (void)out_size;

  // build CSR (counting sort by seg = dst*8 + rel)
  hipLaunchKernelGGL(k_zero, dim3(2048), dim3(256), 0, stream, cntcur, 2 * NSEG);
  hipLaunchKernelGGL(k_edge_hist, dim3((N_EDGESC + 255) / 256), dim3(256), 0, stream,
                     ei, eattr, seg, cnt);
  int nbScan = (NSEG + 4095) / 4096;
  hipLaunchKernelGGL(k_scan1, dim3(nbScan), dim3(256), 0, stream, cnt, offsets + 1, bsums, NSEG);
  hipLaunchKernelGGL(k_scan2, dim3(1), dim3(64), 0, stream, bsums, nbScan);
  hipLaunchKernelGGL(k_scan3, dim3((NSEG + 255) / 256), dim3(256), 0, stream, offsets, bsums, NSEG);
  hipLaunchKernelGGL(k_scatter, dim3((N_EDGESC + 255) / 256), dim3(256), 0, stream,
                     ei, seg, offsets, cursor, ssrc);

  // 3 fused RGCN layers
  int nblk = (N_NODESC + TM - 1) / TM;
  hipLaunchKernelGGL(k_layer, dim3(nblk), dim3(256), 0, stream, x,  W1, r1, b1, offsets, ssrc, h1);
  hipLaunchKernelGGL(k_layer, dim3(nblk), dim3(256), 0, stream, h1, W2, r2, b2, offsets, ssrc, h2);
  hipLaunchKernelGGL(k_layer, dim3(nblk), dim3(256), 0, stream, h2, W3, r3, b3, offsets, ssrc, h1);

  // pool + final linear
  hipLaunchKernelGGL(k_pool, dim3(NGRAPH), dim3(FEAT), 0, stream, h1, batch, lw, lb, out);
}

// Round 2
// 1973.682 us; speedup vs baseline: 2.1533x; 2.1533x over previous
//
#include <hip/hip_runtime.h>

#define N_NODESC 50000
#define N_EDGESC 1600000
#define FEAT 128
#define NREL 8
#define NSEG (N_NODESC * NREL)
#define NGRAPH 64

static inline size_t align256(size_t x) { return (x + 255) & ~(size_t)255; }

// ---------------- utility: zero ints ----------------
__global__ void k_zero(int* __restrict__ p, int n) {
  int i = blockIdx.x * blockDim.x + threadIdx.x;
  int stride = gridDim.x * blockDim.x;
  for (; i < n; i += stride) p[i] = 0;
}

// ---------------- edge type + segment + histogram ----------------
__global__ void k_edge_hist(const int* __restrict__ ei, const float* __restrict__ eattr,
                            int* __restrict__ seg, int* __restrict__ cnt) {
  int e = blockIdx.x * blockDim.x + threadIdx.x;
  if (e >= N_EDGESC) return;
  int dst = ei[N_EDGESC + e];  // row 1
  const float4* ap = (const float4*)(eattr + (size_t)e * 8);
  float4 a0 = ap[0], a1 = ap[1];
  int ty = 0;
  if (a0.y > 0.5f) ty = 1;
  if (a0.z > 0.5f) ty = 2;
  if (a0.w > 0.5f) ty = 3;
  if (a1.x > 0.5f) ty = 4;
  if (a1.y > 0.5f) ty = 5;
  if (a1.z > 0.5f) ty = 6;
  if (a1.w > 0.5f) ty = 7;
  int s = dst * NREL + ty;
  seg[e] = s;
  atomicAdd(&cnt[s], 1);
}

// ---------------- scan over NSEG counts ----------------
__global__ void k_scan1(const int* __restrict__ cnt, int* __restrict__ outIncl,
                        int* __restrict__ bsums, int n) {
  __shared__ int sd[256];
  int t = threadIdx.x;
  int base = blockIdx.x * 4096 + t * 16;
  int v[16];
  int s = 0;
#pragma unroll
  for (int j = 0; j < 16; ++j) {
    int idx = base + j;
    int x = (idx < n) ? cnt[idx] : 0;
    s += x;
    v[j] = s;
  }
  sd[t] = s;
  __syncthreads();
  for (int off = 1; off < 256; off <<= 1) {
    int add = (t >= off) ? sd[t - off] : 0;
    __syncthreads();
    sd[t] += add;
    __syncthreads();
  }
  int prev = (t > 0) ? sd[t - 1] : 0;
#pragma unroll
  for (int j = 0; j < 16; ++j) {
    int idx = base + j;
    if (idx < n) outIncl[idx] = prev + v[j];
  }
  if (t == 255) bsums[blockIdx.x] = sd[255];
}

// parallel exclusive scan of block sums (nb <= 128)
__global__ void k_scan2(int* __restrict__ bsums, int nb) {
  __shared__ int sd[128];
  int t = threadIdx.x;
  int v = (t < nb) ? bsums[t] : 0;
  sd[t] = v;
  __syncthreads();
  for (int off = 1; off < 128; off <<= 1) {
    int add = (t >= off) ? sd[t - off] : 0;
    __syncthreads();
    sd[t] += add;
    __syncthreads();
  }
  if (t < nb) bsums[t] = sd[t] - v;  // exclusive
}

__global__ void k_scan3(int* __restrict__ offsets, const int* __restrict__ bsums, int n) {
  int i = blockIdx.x * blockDim.x + threadIdx.x;
  if (i == 0) offsets[0] = 0;
  if (i < n) offsets[i + 1] += bsums[i >> 12];  // 4096 per chunk
}

// ---------------- scatter into CSR ----------------
__global__ void k_scatter(const int* __restrict__ ei, const int* __restrict__ seg,
                          const int* __restrict__ offsets, int* __restrict__ cursor,
                          int* __restrict__ ssrc) {
  int e = blockIdx.x * blockDim.x + threadIdx.x;
  if (e >= N_EDGESC) return;
  int s = seg[e];
  int p = offsets[s] + atomicAdd(&cursor[s], 1);
  ssrc[p] = ei[e];  // src = row 0
}

// ---------------- segment-parallel mean aggregation ----------------
// one 32-lane group per segment; lane l handles features [4l, 4l+4)
__global__ __launch_bounds__(256, 8) void k_agg(
    const float* __restrict__ in, const int* __restrict__ offsets,
    const int* __restrict__ ssrc, float* __restrict__ agg,
    int segBase, int segCount) {
  int t = blockIdx.x * blockDim.x + threadIdx.x;
  int ul = t >> 5;  // chunk-local segment
  int l = t & 31;
  if (ul >= segCount) return;
  int u = segBase + ul;
  int beg = offsets[u], end = offsets[u + 1];
  float4 s = make_float4(0.f, 0.f, 0.f, 0.f);
  for (int e = beg; e < end; ++e) {
    const float4 v = *(const float4*)&in[(size_t)ssrc[e] * FEAT + l * 4];
    s.x += v.x; s.y += v.y; s.z += v.z; s.w += v.w;
  }
  int c = end - beg;
  if (c > 1) {
    float inv = 1.0f / (float)c;
    s.x *= inv; s.y *= inv; s.z *= inv; s.w *= inv;
  }
  *(float4*)&agg[(size_t)ul * FEAT + l * 4] = s;
}

// ---------------- GEMM: out = relu(agg@Wflat + x@root + bias) ----------------
// block tile 128m x 128n, 256 threads, 8x8 per-thread tile, K = 1024 + 128
__global__ __launch_bounds__(256, 3) void k_gemm(
    const float* __restrict__ aggc,  // [rowsInChunk][1024] chunk-local
    const float* __restrict__ xin,   // [N][128] global (layer input)
    const float* __restrict__ W,     // [1024][128]
    const float* __restrict__ root,  // [128][128]
    const float* __restrict__ bias, float* __restrict__ out,
    int n0g, int rowsInChunk) {
  __shared__ float aS[32][132];
  __shared__ float wS[32][132];
  const int t = threadIdx.x;
  const int tx = t & 15, ty = t >> 4;
  const int m0 = blockIdx.x * 128;
  const int mrow = t >> 1, half = t & 1;  // A staging: 2 threads/row
  const int wrow = t >> 3, wseg = t & 7;  // W staging: 8 threads/row

  float acc[8][8];
#pragma unroll
  for (int a = 0; a < 8; ++a)
#pragma unroll
    for (int b = 0; b < 8; ++b) acc[a][b] = 0.f;

  for (int kc = 0; kc < 36; ++kc) {
    const bool isRoot = (kc >= 32);
    float av[16];
    {
      int gm = m0 + mrow;
      if (gm < rowsInChunk) {
        const float* src = isRoot
            ? (xin + (size_t)(n0g + gm) * FEAT + (kc - 32) * 32 + half * 16)
            : (aggc + (size_t)gm * 1024 + kc * 32 + half * 16);
#pragma unroll
        for (int j = 0; j < 4; ++j) *(float4*)&av[j * 4] = ((const float4*)src)[j];
      } else {
#pragma unroll
        for (int j = 0; j < 16; ++j) av[j] = 0.f;
      }
    }
    float wv[16];
    {
      const float* wsrc = (isRoot ? root + (size_t)(kc - 32) * 32 * FEAT
                                  : W + (size_t)kc * 32 * FEAT) +
                          wrow * FEAT + wseg * 16;
#pragma unroll
      for (int j = 0; j < 4; ++j) *(float4*)&wv[j * 4] = ((const float4*)wsrc)[j];
    }
    __syncthreads();  // previous iteration's reads done before overwrite
#pragma unroll
    for (int j = 0; j < 16; ++j) aS[half * 16 + j][mrow] = av[j];  // transpose store
#pragma unroll
    for (int j = 0; j < 4; ++j) *(float4*)&wS[wrow][wseg * 16 + j * 4] = *(float4*)&wv[j * 4];
    __syncthreads();

#pragma unroll
    for (int kk = 0; kk < 32; ++kk) {
      float a8[8], w8[8];
      *(float4*)&a8[0] = *(const float4*)&aS[kk][ty * 8];
      *(float4*)&a8[4] = *(const float4*)&aS[kk][ty * 8 + 4];
      *(float4*)&w8[0] = *(const float4*)&wS[kk][tx * 8];
      *(float4*)&w8[4] = *(const float4*)&wS[kk][tx * 8 + 4];
#pragma unroll
      for (int a = 0; a < 8; ++a)
#pragma unroll
        for (int b = 0; b < 8; ++b)
          acc[a][b] = fmaf(a8[a], w8[b], acc[a][b]);
    }
  }

  float bia[8];
  *(float4*)&bia[0] = *(const float4*)&bias[tx * 8];
  *(float4*)&bia[4] = *(const float4*)&bias[tx * 8 + 4];
#pragma unroll
  for (int a = 0; a < 8; ++a) {
    int gm = m0 + ty * 8 + a;
    if (gm < rowsInChunk) {
      float o[8];
#pragma unroll
      for (int b = 0; b < 8; ++b) {
        float v = acc[a][b] + bia[b];
        o[b] = v > 0.f ? v : 0.f;
      }
      *(float4*)&out[(size_t)(n0g + gm) * FEAT + tx * 8] = *(float4*)&o[0];
      *(float4*)&out[(size_t)(n0g + gm) * FEAT + tx * 8 + 4] = *(float4*)&o[4];
    }
  }
}

// ---------------- global mean pool + final linear (8-way node-parallel) ----------------
__global__ void k_pool(const float* __restrict__ h, const int* __restrict__ batch,
                       const float* __restrict__ lw, const float* __restrict__ lb,
                       float* __restrict__ out) {
  __shared__ float sums[8][128];
  __shared__ float prow[128];
  int gidx = blockIdx.x, t = threadIdx.x;
  int f = t & 127, grp = t >> 7;
  int lo = 0, hi = N_NODESC;
  while (lo < hi) {
    int mid = (lo + hi) >> 1;
    if (batch[mid] < gidx) lo = mid + 1; else hi = mid;
  }
  int start = lo;
  hi = N_NODESC;
  while (lo < hi) {
    int mid = (lo + hi) >> 1;
    if (batch[mid] < gidx + 1) lo = mid + 1; else hi = mid;
  }
  int end = lo;
  float s = 0.f;
  for (int n = start + grp; n < end; n += 8) s += h[(size_t)n * FEAT + f];
  sums[grp][f] = s;
  __syncthreads();
  if (grp == 0) {
    float tot = 0.f;
#pragma unroll
    for (int gg = 0; gg < 8; ++gg) tot += sums[gg][f];
    int c = end - start;
    prow[f] = (c > 0) ? tot / (float)c : 0.f;
  }
  __syncthreads();
  float a = 0.f;
  for (int k = grp * 16; k < grp * 16 + 16; ++k) a = fmaf(prow[k], lw[(size_t)k * FEAT + f], a);
  __syncthreads();  // done reading sums from phase 1
  sums[grp][f] = a;
  __syncthreads();
  if (grp == 0) {
    float tot = lb[f];
#pragma unroll
    for (int gg = 0; gg < 8; ++gg) tot += sums[gg][f];
    out[(size_t)gidx * FEAT + f] = tot;
  }
}

extern "C" void kernel_launch(void* const* d_in, const int* in_sizes, int n_in,
                              void* d_out, int out_size, void* d_ws, size_t ws_size,
                              hipStream_t stream) {
  const float* x = (const float*)d_in[0];
  const int* ei = (const int*)d_in[1];
  const float* eattr = (const float*)d_in[2];
  const int* batch = (const int*)d_in[3];
  const float* Wl[3] = {(const float*)d_in[4], (const float*)d_in[7], (const float*)d_in[10]};
  const float* rl[3] = {(const float*)d_in[5], (const float*)d_in[8], (const float*)d_in[11]};
  const float* bl[3] = {(const float*)d_in[6], (const float*)d_in[9], (const float*)d_in[12]};
  const float* lw = (const float*)d_in[13];
  const float* lb = (const float*)d_in[14];
  float* out = (float*)d_out;
  (void)n_in; (void)in_sizes; (void)out_size;

  // ---- workspace carve ----
  size_t pos = 0;
  char* base = (char*)d_ws;
  auto alloc = [&](size_t bytes) { char* q = base + pos; pos += align256(bytes); return q; };
  int* seg = (int*)alloc(sizeof(int) * (size_t)N_EDGESC);
  int* cntcur = (int*)alloc(sizeof(int) * (size_t)2 * NSEG);
  int* cnt = cntcur;
  int* cursor = cntcur + NSEG;
  int* offsets = (int*)alloc(sizeof(int) * (size_t)(NSEG + 1));
  int* bsums = (int*)alloc(sizeof(int) * 1024);
  int* ssrc = (int*)alloc(sizeof(int) * (size_t)N_EDGESC);
  float* h1 = (float*)alloc(sizeof(float) * (size_t)N_NODESC * FEAT);
  float* h2 = (float*)alloc(sizeof(float) * (size_t)N_NODESC * FEAT);
  // agg chunk buffer takes the remainder (4 KB per node needed)
  size_t remain = (ws_size > pos) ? (ws_size - pos) : 0;
  long long cn = (long long)(remain / (sizeof(float) * NREL * FEAT));
  int chunkNodes = (cn > N_NODESC) ? N_NODESC : (int)cn;
  chunkNodes &= ~127;
  if (chunkNodes < 128) chunkNodes = 128;  // last resort
  float* aggbuf = (float*)(base + pos);
  int nchunks = (N_NODESC + chunkNodes - 1) / chunkNodes;

  // ---- build CSR (counting sort by seg = dst*8 + rel) ----
  hipLaunchKernelGGL(k_zero, dim3(2048), dim3(256), 0, stream, cntcur, 2 * NSEG);
  hipLaunchKernelGGL(k_edge_hist, dim3((N_EDGESC + 255) / 256), dim3(256), 0, stream,
                     ei, eattr, seg, cnt);
  int nbScan = (NSEG + 4095) / 4096;  // 98
  hipLaunchKernelGGL(k_scan1, dim3(nbScan), dim3(256), 0, stream, cnt, offsets + 1, bsums, NSEG);
  hipLaunchKernelGGL(k_scan2, dim3(1), dim3(128), 0, stream, bsums, nbScan);
  hipLaunchKernelGGL(k_scan3, dim3((NSEG + 255) / 256), dim3(256), 0, stream, offsets, bsums, NSEG);
  hipLaunchKernelGGL(k_scatter, dim3((N_EDGESC + 255) / 256), dim3(256), 0, stream,
                     ei, seg, offsets, cursor, ssrc);

  // ---- 3 RGCN layers: per chunk {aggregate, gemm} ----
  const float* inPtr = x;
  float* outPtr = h1;
  for (int L = 0; L < 3; ++L) {
    for (int c = 0; c < nchunks; ++c) {
      int nodeBase = c * chunkNodes;
      int rows = N_NODESC - nodeBase;
      if (rows > chunkNodes) rows = chunkNodes;
      int segCount = rows * NREL;
      int aggBlocks = (segCount * 32 + 255) / 256;
      hipLaunchKernelGGL(k_agg, dim3(aggBlocks), dim3(256), 0, stream,
                         inPtr, offsets, ssrc, aggbuf, nodeBase * NREL, segCount);
      hipLaunchKernelGGL(k_gemm, dim3((rows + 127) / 128), dim3(256), 0, stream,
                         aggbuf, inPtr, Wl[L], rl[L], bl[L], outPtr, nodeBase, rows);
    }
    inPtr = outPtr;
    outPtr = (L == 0) ? h2 : h1;
  }

  // ---- pool + final linear ----
  hipLaunchKernelGGL(k_pool, dim3(NGRAPH), dim3(1024), 0, stream, h1, batch, lw, lb, out);
}

// Round 5
// 1003.259 us; speedup vs baseline: 4.2362x; 1.9673x over previous
//
#include <hip/hip_runtime.h>

#define N_NODESC 50000
#define N_EDGESC 1600000
#define FEAT 128
#define NREL 8
#define NSEG (N_NODESC * NREL)
#define NGRAPH 64
#define KTOT 1152          // 8*128 agg + 128 root
#define NKC 36             // KTOT/32
#define WPACK_ELEMS (NKC * 4 * 128 * 8)  // 147456

typedef float f32x4 __attribute__((ext_vector_type(4)));
typedef short bf16x8 __attribute__((ext_vector_type(8)));

static inline size_t align256(size_t x) { return (x + 255) & ~(size_t)255; }

__device__ __forceinline__ unsigned short f2bf(float f) {
  unsigned int u = __float_as_uint(f);
  unsigned int r = (u + 0x7fffu + ((u >> 16) & 1u)) >> 16;  // RNE
  return (unsigned short)r;
}
__device__ __forceinline__ float bf2f(unsigned short h) {
  return __uint_as_float(((unsigned int)h) << 16);
}

// ---------------- utility: zero ints ----------------
__global__ void k_zero(int* __restrict__ p, int n) {
  int i = blockIdx.x * blockDim.x + threadIdx.x;
  int stride = gridDim.x * blockDim.x;
  for (; i < n; i += stride) p[i] = 0;
}

// ---------------- edge type + segment + histogram ----------------
__global__ void k_edge_hist(const int* __restrict__ ei, const float* __restrict__ eattr,
                            int* __restrict__ seg, int* __restrict__ cnt) {
  int e = blockIdx.x * blockDim.x + threadIdx.x;
  if (e >= N_EDGESC) return;
  int dst = ei[N_EDGESC + e];
  const float4* ap = (const float4*)(eattr + (size_t)e * 8);
  float4 a0 = ap[0], a1 = ap[1];
  int ty = 0;
  if (a0.y > 0.5f) ty = 1;
  if (a0.z > 0.5f) ty = 2;
  if (a0.w > 0.5f) ty = 3;
  if (a1.x > 0.5f) ty = 4;
  if (a1.y > 0.5f) ty = 5;
  if (a1.z > 0.5f) ty = 6;
  if (a1.w > 0.5f) ty = 7;
  int s = dst * NREL + ty;
  seg[e] = s;
  atomicAdd(&cnt[s], 1);
}

// ---------------- scan over NSEG counts ----------------
__global__ void k_scan1(const int* __restrict__ cnt, int* __restrict__ outIncl,
                        int* __restrict__ bsums, int n) {
  __shared__ int sd[256];
  int t = threadIdx.x;
  int base = blockIdx.x * 4096 + t * 16;
  int v[16];
  int s = 0;
#pragma unroll
  for (int j = 0; j < 16; ++j) {
    int idx = base + j;
    int x = (idx < n) ? cnt[idx] : 0;
    s += x;
    v[j] = s;
  }
  sd[t] = s;
  __syncthreads();
  for (int off = 1; off < 256; off <<= 1) {
    int add = (t >= off) ? sd[t - off] : 0;
    __syncthreads();
    sd[t] += add;
    __syncthreads();
  }
  int prev = (t > 0) ? sd[t - 1] : 0;
#pragma unroll
  for (int j = 0; j < 16; ++j) {
    int idx = base + j;
    if (idx < n) outIncl[idx] = prev + v[j];
  }
  if (t == 255) bsums[blockIdx.x] = sd[255];
}

__global__ void k_scan2(int* __restrict__ bsums, int nb) {
  __shared__ int sd[128];
  int t = threadIdx.x;
  int v = (t < nb) ? bsums[t] : 0;
  sd[t] = v;
  __syncthreads();
  for (int off = 1; off < 128; off <<= 1) {
    int add = (t >= off) ? sd[t - off] : 0;
    __syncthreads();
    sd[t] += add;
    __syncthreads();
  }
  if (t < nb) bsums[t] = sd[t] - v;  // exclusive
}

__global__ void k_scan3(int* __restrict__ offsets, const int* __restrict__ bsums, int n) {
  int i = blockIdx.x * blockDim.x + threadIdx.x;
  if (i == 0) offsets[0] = 0;
  if (i < n) offsets[i + 1] += bsums[i >> 12];
}

// ---------------- scatter into CSR ----------------
__global__ void k_scatter(const int* __restrict__ ei, const int* __restrict__ seg,
                          const int* __restrict__ offsets, int* __restrict__ cursor,
                          int* __restrict__ ssrc) {
  int e = blockIdx.x * blockDim.x + threadIdx.x;
  if (e >= N_EDGESC) return;
  int s = seg[e];
  int p = offsets[s] + atomicAdd(&cursor[s], 1);
  ssrc[p] = ei[e];
}

// ---------------- segment-parallel mean aggregation ----------------
__global__ __launch_bounds__(256, 8) void k_agg(
    const float* __restrict__ in, const int* __restrict__ offsets,
    const int* __restrict__ ssrc, float* __restrict__ agg,
    int segBase, int segCount) {
  int t = blockIdx.x * blockDim.x + threadIdx.x;
  int ul = t >> 5;
  int l = t & 31;
  if (ul >= segCount) return;
  int u = segBase + ul;
  int beg = offsets[u], end = offsets[u + 1];
  float4 s = make_float4(0.f, 0.f, 0.f, 0.f);
  for (int e = beg; e < end; ++e) {
    const float4 v = *(const float4*)&in[(size_t)ssrc[e] * FEAT + l * 4];
    s.x += v.x; s.y += v.y; s.z += v.z; s.w += v.w;
  }
  int c = end - beg;
  if (c > 1) {
    float inv = 1.0f / (float)c;
    s.x *= inv; s.y *= inv; s.z *= inv; s.w *= inv;
  }
  *(float4*)&agg[(size_t)ul * FEAT + l * 4] = s;
}

// ---------------- weight pack: W[8][128][128] + root[128][128] -> bf16 hi/lo ----------------
// fragment-major layout: idx = ((slot*128)+n)*8 + j, slot = kc*4+g, k = kc*32+g*8+j
__global__ void k_wpack(const float* __restrict__ W, const float* __restrict__ root,
                        unsigned short* __restrict__ whi, unsigned short* __restrict__ wlo) {
  int idx = blockIdx.x * 256 + threadIdx.x;
  if (idx >= WPACK_ELEMS) return;
  int j = idx & 7;
  int n = (idx >> 3) & 127;
  int slot = idx >> 10;
  int k = slot * 8 + j;
  float v = (k < 1024) ? W[(size_t)k * 128 + n] : root[(size_t)(k - 1024) * 128 + n];
  unsigned short hi = f2bf(v);
  float lof = v - bf2f(hi);
  whi[idx] = hi;
  wlo[idx] = f2bf(lof);
}

// ---------------- MFMA GEMM: out = relu(A @ Wfull + bias), A = [agg | x], K=1152 ----------------
// block: 128 rows x 128 cols, 256 threads (4 waves), wave = 32 rows x 128 cols
__global__ __launch_bounds__(256, 2) void k_gemm_mfma(
    const float* __restrict__ aggc,  // [rows][1024] chunk-local
    const float* __restrict__ xin,   // [N][128]
    const unsigned short* __restrict__ Whi, const unsigned short* __restrict__ Wlo,
    const float* __restrict__ bias, float* __restrict__ out,
    int n0g, int rows) {
  __shared__ unsigned short Ahi[4 * 128 * 8] __attribute__((aligned(16)));  // [g][row][j]
  __shared__ unsigned short Alo[4 * 128 * 8] __attribute__((aligned(16)));
  __shared__ unsigned short Bhi[4 * 128 * 8] __attribute__((aligned(16)));  // [g][n][j]
  __shared__ unsigned short Blo[4 * 128 * 8] __attribute__((aligned(16)));

  const int t = threadIdx.x;
  const int lane = t & 63, wave = t >> 6;
  const int l15 = lane & 15, lg = lane >> 4;
  const int wrow0 = wave * 32;
  const int m0 = blockIdx.x * 128;
  const int srow = t >> 1, half = t & 1;

  f32x4 acc[2][8];
#pragma unroll
  for (int a = 0; a < 2; ++a)
#pragma unroll
    for (int b = 0; b < 8; ++b) acc[a][b] = (f32x4){0.f, 0.f, 0.f, 0.f};

  for (int kc = 0; kc < NKC; ++kc) {
    // ---- load A slab (fp32) ----
    int rowc = srow;
    if (m0 + rowc >= rows) rowc = rows - 1 - m0;  // clamp (garbage rows masked later)
    if (rowc < 0) rowc = 0;
    const float* asrc = (kc < 32)
        ? (aggc + (size_t)(m0 + rowc) * 1024 + kc * 32 + half * 16)
        : (xin + (size_t)(n0g + m0 + rowc) * FEAT + (kc - 32) * 32 + half * 16);
    float4 av[4];
#pragma unroll
    for (int q = 0; q < 4; ++q) av[q] = ((const float4*)asrc)[q];
    // ---- load B slab (already packed bf16 hi/lo, contiguous 8KB each) ----
    const uint4* bhs = (const uint4*)(Whi + (size_t)kc * 4096);
    const uint4* bls = (const uint4*)(Wlo + (size_t)kc * 4096);
    uint4 bh0 = bhs[t * 2], bh1 = bhs[t * 2 + 1];
    uint4 bl0 = bls[t * 2], bl1 = bls[t * 2 + 1];

    __syncthreads();  // previous iteration's LDS reads complete

    // ---- convert + pack A into LDS ----
    const float* avf = (const float*)av;
#pragma unroll
    for (int gg = 0; gg < 2; ++gg) {
      union { unsigned short u[8]; uint4 v; } ph, pl;
#pragma unroll
      for (int j = 0; j < 8; ++j) {
        float f = avf[gg * 8 + j];
        unsigned short hi = f2bf(f);
        ph.u[j] = hi;
        pl.u[j] = f2bf(f - bf2f(hi));
      }
      int g = half * 2 + gg;
      *(uint4*)&Ahi[((size_t)(g * 128 + srow)) * 8] = ph.v;
      *(uint4*)&Alo[((size_t)(g * 128 + srow)) * 8] = pl.v;
    }
    // ---- store B into LDS (straight copy) ----
    ((uint4*)Bhi)[t * 2] = bh0;
    ((uint4*)Bhi)[t * 2 + 1] = bh1;
    ((uint4*)Blo)[t * 2] = bl0;
    ((uint4*)Blo)[t * 2 + 1] = bl1;

    __syncthreads();

    // ---- fragments + MFMA ----
    bf16x8 ah[2], al[2];
#pragma unroll
    for (int mf = 0; mf < 2; ++mf) {
      int ar = wrow0 + mf * 16 + l15;
      ah[mf] = *(const bf16x8*)&Ahi[((size_t)(lg * 128 + ar)) * 8];
      al[mf] = *(const bf16x8*)&Alo[((size_t)(lg * 128 + ar)) * 8];
    }
#pragma unroll
    for (int nf = 0; nf < 8; ++nf) {
      int bn = nf * 16 + l15;
      bf16x8 bh = *(const bf16x8*)&Bhi[((size_t)(lg * 128 + bn)) * 8];
      bf16x8 bl = *(const bf16x8*)&Blo[((size_t)(lg * 128 + bn)) * 8];
#pragma unroll
      for (int mf = 0; mf < 2; ++mf) {
        acc[mf][nf] = __builtin_amdgcn_mfma_f32_16x16x32_bf16(ah[mf], bh, acc[mf][nf], 0, 0, 0);
        acc[mf][nf] = __builtin_amdgcn_mfma_f32_16x16x32_bf16(ah[mf], bl, acc[mf][nf], 0, 0, 0);
        acc[mf][nf] = __builtin_amdgcn_mfma_f32_16x16x32_bf16(al[mf], bh, acc[mf][nf], 0, 0, 0);
      }
    }
  }

  // ---- epilogue: bias + relu + store ----
  float bcol[8];
#pragma unroll
  for (int nf = 0; nf < 8; ++nf) bcol[nf] = bias[nf * 16 + l15];
#pragma unroll
  for (int mf = 0; mf < 2; ++mf)
#pragma unroll
    for (int nf = 0; nf < 8; ++nf)
#pragma unroll
      for (int j = 0; j < 4; ++j) {
        int grow = m0 + wrow0 + mf * 16 + lg * 4 + j;
        if (grow < rows) {
          float v = acc[mf][nf][j] + bcol[nf];
          v = v > 0.f ? v : 0.f;
          out[(size_t)(n0g + grow) * FEAT + nf * 16 + l15] = v;
        }
      }
}

// ---------------- global mean pool + final linear ----------------
__global__ void k_pool(const float* __restrict__ h, const int* __restrict__ batch,
                       const float* __restrict__ lw, const float* __restrict__ lb,
                       float* __restrict__ out) {
  __shared__ float sums[8][128];
  __shared__ float prow[128];
  int gidx = blockIdx.x, t = threadIdx.x;
  int f = t & 127, grp = t >> 7;
  int lo = 0, hi = N_NODESC;
  while (lo < hi) {
    int mid = (lo + hi) >> 1;
    if (batch[mid] < gidx) lo = mid + 1; else hi = mid;
  }
  int start = lo;
  hi = N_NODESC;
  while (lo < hi) {
    int mid = (lo + hi) >> 1;
    if (batch[mid] < gidx + 1) lo = mid + 1; else hi = mid;
  }
  int end = lo;
  float s = 0.f;
  for (int n = start + grp; n < end; n += 8) s += h[(size_t)n * FEAT + f];
  sums[grp][f] = s;
  __syncthreads();
  if (grp == 0) {
    float tot = 0.f;
#pragma unroll
    for (int gg = 0; gg < 8; ++gg) tot += sums[gg][f];
    int c = end - start;
    prow[f] = (c > 0) ? tot / (float)c : 0.f;
  }
  __syncthreads();
  float a = 0.f;
  for (int k = grp * 16; k < grp * 16 + 16; ++k) a = fmaf(prow[k], lw[(size_t)k * FEAT + f], a);
  __syncthreads();
  sums[grp][f] = a;
  __syncthreads();
  if (grp == 0) {
    float tot = lb[f];
#pragma unroll
    for (int gg = 0; gg < 8; ++gg) tot += sums[gg][f];
    out[(size_t)gidx * FEAT + f] = tot;
  }
}

extern "C" void kernel_launch(void* const* d_in, const int* in_sizes, int n_in,
                              void* d_out, int out_size, void* d_ws, size_t ws_size,
                              hipStream_t stream) {
  const float* x = (const float*)d_in[0];
  const int* ei = (const int*)d_in[1];
  const float* eattr = (const float*)d_in[2];
  const int* batch = (const int*)d_in[3];
  const float* Wl[3] = {(const float*)d_in[4], (const float*)d_in[7], (const float*)d_in[10]};
  const float* rl[3] = {(const float*)d_in[5], (const float*)d_in[8], (const float*)d_in[11]};
  const float* bl[3] = {(const float*)d_in[6], (const float*)d_in[9], (const float*)d_in[12]};
  const float* lw = (const float*)d_in[13];
  const float* lb = (const float*)d_in[14];
  float* out = (float*)d_out;
  (void)n_in; (void)in_sizes; (void)out_size;

  // ---- workspace carve ----
  size_t pos = 0;
  char* base = (char*)d_ws;
  auto alloc = [&](size_t bytes) { char* q = base + pos; pos += align256(bytes); return q; };
  int* seg = (int*)alloc(sizeof(int) * (size_t)N_EDGESC);
  int* cntcur = (int*)alloc(sizeof(int) * (size_t)2 * NSEG);
  int* cnt = cntcur;
  int* cursor = cntcur + NSEG;
  int* offsets = (int*)alloc(sizeof(int) * (size_t)(NSEG + 1));
  int* bsums = (int*)alloc(sizeof(int) * 1024);
  int* ssrc = (int*)alloc(sizeof(int) * (size_t)N_EDGESC);
  float* h1 = (float*)alloc(sizeof(float) * (size_t)N_NODESC * FEAT);
  float* h2 = (float*)alloc(sizeof(float) * (size_t)N_NODESC * FEAT);
  unsigned short* whi = (unsigned short*)alloc(sizeof(unsigned short) * (size_t)WPACK_ELEMS);
  unsigned short* wlo = (unsigned short*)alloc(sizeof(unsigned short) * (size_t)WPACK_ELEMS);
  size_t remain = (ws_size > pos) ? (ws_size - pos) : 0;
  long long cn = (long long)(remain / (sizeof(float) * NREL * FEAT));
  int chunkNodes = (cn > N_NODESC) ? N_NODESC : (int)cn;
  chunkNodes &= ~127;
  if (chunkNodes < 128) chunkNodes = 128;
  float* aggbuf = (float*)(base + pos);
  int nchunks = (N_NODESC + chunkNodes - 1) / chunkNodes;

  // ---- build CSR ----
  hipLaunchKernelGGL(k_zero, dim3(2048), dim3(256), 0, stream, cntcur, 2 * NSEG);
  hipLaunchKernelGGL(k_edge_hist, dim3((N_EDGESC + 255) / 256), dim3(256), 0, stream,
                     ei, eattr, seg, cnt);
  int nbScan = (NSEG + 4095) / 4096;  // 98
  hipLaunchKernelGGL(k_scan1, dim3(nbScan), dim3(256), 0, stream, cnt, offsets + 1, bsums, NSEG);
  hipLaunchKernelGGL(k_scan2, dim3(1), dim3(128), 0, stream, bsums, nbScan);
  hipLaunchKernelGGL(k_scan3, dim3((NSEG + 255) / 256), dim3(256), 0, stream, offsets, bsums, NSEG);
  hipLaunchKernelGGL(k_scatter, dim3((N_EDGESC + 255) / 256), dim3(256), 0, stream,
                     ei, seg, offsets, cursor, ssrc);

  // ---- 3 RGCN layers ----
  const float* inPtr = x;
  float* outPtr = h1;
  for (int L = 0; L < 3; ++L) {
    hipLaunchKernelGGL(k_wpack, dim3((WPACK_ELEMS + 255) / 256), dim3(256), 0, stream,
                       Wl[L], rl[L], whi, wlo);
    for (int c = 0; c < nchunks; ++c) {
      int nodeBase = c * chunkNodes;
      int rowsC = N_NODESC - nodeBase;
      if (rowsC > chunkNodes) rowsC = chunkNodes;
      int segCount = rowsC * NREL;
      int aggBlocks = (segCount * 32 + 255) / 256;
      hipLaunchKernelGGL(k_agg, dim3(aggBlocks), dim3(256), 0, stream,
                         inPtr, offsets, ssrc, aggbuf, nodeBase * NREL, segCount);
      hipLaunchKernelGGL(k_gemm_mfma, dim3((rowsC + 127) / 128), dim3(256), 0, stream,
                         aggbuf, inPtr, whi, wlo, bl[L], outPtr, nodeBase, rowsC);
    }
    inPtr = outPtr;
    outPtr = (L == 0) ? h2 : h1;
  }

  // ---- pool + final linear ----
  hipLaunchKernelGGL(k_pool, dim3(NGRAPH), dim3(1024), 0, stream, h1, batch, lw, lb, out);
}